// Round 4
// baseline (69.252 us; speedup 1.0000x reference)
//
#include <hip/hip_runtime.h>

// KnnConvUnit: B=4, N=8192, K=16, C=64, HID=OUT=128.
// out[b,n,:] = (max_k relu(relu(x@W1+b1)@W2+b2)) @ W3 + b3,
//   x = [f, knn, knn-f]  ->  h1 = relu([knn | f] @ [[Bm],[Aw]] + b1)
//   Bm = W1[64:128]+W1[128:192], Aw = W1[0:64]-W1[128:192]  (K=128 folded GEMM)
// v_mfma_f32_16x16x32_f16 everywhere, shared k-permutation
//   kappa(g,j) = 16*(j>>2) + 4*g + (j&3)
// Round-4 deltas vs round-2 (55us):
//   * W2 frags read from GLOBAL ws (L1/L2-resident, coalesced) -- not LDS
//   * LDS = Bm-folded 32KB + pooled 4KB = 36864B -> 3-4 blocks/CU occupancy
//   * one-shot blocks (16 pts), grid 2048, 2 barriers total -- no iter loop

#define BB 4
#define NN 8192
#define KK 16
#define CC 64
#define HH 128

typedef _Float16 f16;
typedef _Float16 f16x8 __attribute__((ext_vector_type(8)));
typedef float f32x4 __attribute__((ext_vector_type(4)));

#define MFMA16(a, b, c) __builtin_amdgcn_mfma_f32_16x16x32_f16(a, b, c, 0, 0, 0)

// ---------------- prep: pack weights, fragment-linear f16, kappa k-order ----
// fid 0..31 : L1 A-frags (ht=fid>>2, kt=fid&3): kt<2 -> Bm, kt>=2 -> Aw
// fid 32..63: L2 B-frags (h2t, kt): W2[k][h2t*16+r]
// fid 64..95: L3 A-frags (ot, kt):  W3[k][ot*16+r]
__global__ void prep_pack(const float* __restrict__ W1, const float* __restrict__ W2,
                          const float* __restrict__ W3, f16* __restrict__ ws) {
  int fid = blockIdx.x;
  int l = threadIdx.x;
  int g = l >> 4, r = l & 15;
  f16x8 v;
#pragma unroll
  for (int j = 0; j < 8; ++j) {
    int kl = 16 * (j >> 2) + 4 * g + (j & 3);   // kappa(g,j)
    float x;
    if (fid < 32) {
      int ht = fid >> 2, kt = fid & 3, h = ht * 16 + r;
      if (kt < 2) {
        int k = kt * 32 + kl;
        x = W1[(64 + k) * HH + h] + W1[(128 + k) * HH + h];   // Bm
      } else {
        int k = (kt - 2) * 32 + kl;
        x = W1[k * HH + h] - W1[(128 + k) * HH + h];          // Aw
      }
    } else if (fid < 64) {
      int t = fid - 32, h2t = t >> 2, kt = t & 3;
      x = W2[(kt * 32 + kl) * HH + h2t * 16 + r];
    } else {
      int t = fid - 64, ot = t >> 2, kt = t & 3;
      x = W3[(kt * 32 + kl) * HH + ot * 16 + r];
    }
    v[j] = (f16)x;
  }
  *(f16x8*)(ws + (size_t)fid * 512 + l * 8) = v;
}

// ---------------- main: 16 points/block, 8 waves, 2 pts/wave ----------------
// LDS: wbuf 32 frags (32KB, L1-folded weights) + pooled 4 frags (4KB) = 36864B
__global__ __launch_bounds__(512, 6) void knn_main(
    const float* __restrict__ f, const int* __restrict__ knn,
    const float* __restrict__ b1, const float* __restrict__ b2,
    const float* __restrict__ b3, const f16* __restrict__ ws,
    float* __restrict__ out) {
  extern __shared__ char smem[];
  f16* wbuf = (f16*)smem;              // 32*512 f16
  f16* pooled = wbuf + 32 * 512;       // 4*512 f16

  const int tid = threadIdx.x;
  const int wave = tid >> 6, lane = tid & 63;
  const int g = lane >> 4, r = lane & 15;

  // XCD-aware swizzle: 2048 wgs, 8 XCDs -> each XCD owns 256 contiguous wgs
  const int wg = (blockIdx.x & 7) * 256 + (blockIdx.x >> 3);
  const int b = wg >> 9;
  const int n0 = (wg & 511) * 16;
  const float* fb = f + (size_t)b * NN * CC;
  const int p0 = wave * 2;

  // --- issue knn index loads first (longest dependency chain) ---
  int nidx[2];
#pragma unroll
  for (int pp = 0; pp < 2; ++pp)
    nidx[pp] = knn[(size_t)(b * NN + n0 + p0 + pp) * KK + r];

  // --- stage 32 L1 weight frags into LDS (reg-staged, coalesced, linear) ---
  f16x8 st[4];
#pragma unroll
  for (int i = 0; i < 4; ++i)
    st[i] = *(const f16x8*)(ws + (size_t)(i * 512 + tid) * 8);
#pragma unroll
  for (int i = 0; i < 4; ++i)
    *(f16x8*)(wbuf + (size_t)(i * 512 + tid) * 8) = st[i];

  // --- gather B-frags: kt 0,1 = neighbor row (scattered), kt 2,3 = own row ---
  f16x8 bf[2][4];
#pragma unroll
  for (int pp = 0; pp < 2; ++pp) {
    const float* frow = fb + (size_t)nidx[pp] * CC;
    const float* fown = fb + (size_t)(n0 + p0 + pp) * CC;
#pragma unroll
    for (int kt = 0; kt < 4; ++kt) {
      const float* src = (kt < 2) ? (frow + kt * 32) : (fown + (kt - 2) * 32);
      f32x4 a0 = *(const f32x4*)(src + 4 * g);
      f32x4 a1 = *(const f32x4*)(src + 4 * g + 16);
#pragma unroll
      for (int jl = 0; jl < 4; ++jl) {
        bf[pp][kt][jl] = (f16)a0[jl];
        bf[pp][kt][4 + jl] = (f16)a1[jl];
      }
    }
  }

  __syncthreads();   // (1) wbuf ready

  // --- L1: C[h][nbr] = [Bm;Aw]^T x [knn;f], K=128; h1 -> registers ---
  f16x8 h1f[2][4];
#pragma unroll
  for (int ht = 0; ht < 8; ++ht) {
    f32x4 acc[2] = {{0.f, 0.f, 0.f, 0.f}, {0.f, 0.f, 0.f, 0.f}};
#pragma unroll
    for (int kt = 0; kt < 4; ++kt) {
      f16x8 wfrag = *(const f16x8*)(wbuf + (size_t)(ht * 4 + kt) * 512 + lane * 8);
      acc[0] = MFMA16(wfrag, bf[0][kt], acc[0]);
      acc[1] = MFMA16(wfrag, bf[1][kt], acc[1]);
    }
    f32x4 b1v = *(const f32x4*)(b1 + ht * 16 + g * 4);
#pragma unroll
    for (int pp = 0; pp < 2; ++pp)
#pragma unroll
      for (int i = 0; i < 4; ++i) {
        float x = acc[pp][i] + b1v[i];
        h1f[pp][ht >> 1][(ht & 1) * 4 + i] = (f16)(x > 0.f ? x : 0.f);
      }
  }

  // --- L2: C[nbr][h2] = h1 x W2 (W2 frags from GLOBAL ws, L1/L2-resident) ---
#pragma unroll
  for (int h2t = 0; h2t < 8; ++h2t) {
    f32x4 c0 = {0.f, 0.f, 0.f, 0.f}, c1 = {0.f, 0.f, 0.f, 0.f};
#pragma unroll
    for (int kt = 0; kt < 4; ++kt) {
      f16x8 w2f = *(const f16x8*)(ws + (size_t)(32 + h2t * 4 + kt) * 512 + lane * 8);
      c0 = MFMA16(h1f[0][kt], w2f, c0);
      c1 = MFMA16(h1f[1][kt], w2f, c1);
    }
    float b2v = b2[h2t * 16 + r];
#pragma unroll
    for (int pp = 0; pp < 2; ++pp) {
      f32x4 cc = pp ? c1 : c0;
      float m = fmaxf(fmaxf(cc[0], cc[1]), fmaxf(cc[2], cc[3]));
      m = fmaxf(m, __shfl_xor(m, 16, 64));
      m = fmaxf(m, __shfl_xor(m, 32, 64));
      float x = m + b2v;
      f16 pv = (f16)(x > 0.f ? x : 0.f);
      if (g == 0) {
        // dest: frag kt3=h2t>>1, lane slot (r>>2)*16 + p, elem (h2t&1)*4 + (r&3)
        pooled[(h2t >> 1) * 512 + ((r >> 2) * 16 + p0 + pp) * 8 +
               (h2t & 1) * 4 + (r & 3)] = pv;
      }
    }
  }

  __syncthreads();   // (2) pooled ready (cross-wave)

  // --- L3: C[od][pt] = W3^T x pooled; wave owns od-tile = wave ---
  {
    f32x4 a3 = {0.f, 0.f, 0.f, 0.f};
#pragma unroll
    for (int kt = 0; kt < 4; ++kt) {
      f16x8 w3f = *(const f16x8*)(ws + (size_t)(64 + wave * 4 + kt) * 512 + lane * 8);
      f16x8 pf = *(const f16x8*)(pooled + kt * 512 + lane * 8);
      a3 = MFMA16(w3f, pf, a3);
    }
    f32x4 b3v = *(const f32x4*)(b3 + wave * 16 + g * 4);
    f32x4 o;
#pragma unroll
    for (int i = 0; i < 4; ++i) o[i] = a3[i] + b3v[i];
    *(f32x4*)(out + ((size_t)b * NN + n0 + r) * HH + wave * 16 + g * 4) = o;
  }
}

extern "C" void kernel_launch(void* const* d_in, const int* in_sizes, int n_in,
                              void* d_out, int out_size, void* d_ws, size_t ws_size,
                              hipStream_t stream) {
  const float* f = (const float*)d_in[0];
  const int* knn = (const int*)d_in[1];
  const float* W1 = (const float*)d_in[2];
  const float* b1 = (const float*)d_in[3];
  const float* W2 = (const float*)d_in[4];
  const float* b2 = (const float*)d_in[5];
  const float* W3 = (const float*)d_in[6];
  const float* b3 = (const float*)d_in[7];
  float* outp = (float*)d_out;
  f16* wsp = (f16*)d_ws;   // 96 frags * 1KB = 96KB scratch

  (void)hipFuncSetAttribute((const void*)knn_main,
                            hipFuncAttributeMaxDynamicSharedMemorySize, 36864);

  prep_pack<<<96, 64, 0, stream>>>(W1, W2, W3, wsp);
  knn_main<<<(BB * NN) / 16, 512, 36864, stream>>>(f, knn, b1, b2, b3, wsp, outp);
}